// Round 4
// baseline (118.815 us; speedup 1.0000x reference)
//
#include <hip/hip_runtime.h>
#include <math.h>

#define NB 8
#define NA 192
#define ND 128
#define NREL 5
#define NH 128
#define ROWS 6
#define KS 4                          // k-split count (384 = 4 x 96)
#define NROWBLK ((NB * NA) / ROWS)    // 256 row-blocks
#define TI 2                          // i-tile in edge kernel
// fan_in = 6*ND + NREL + ND = 901
// W1 rows: [0:128) ci, [128:256) cj, [256:384) gi, [384:512) gj,
//          [512:640) fi, [640:768) fj, [768:773) rel, [773:901) gc

// ---------------- Kernel 1: k-split partial projections + Gc ----------------
// blk < KS*NROWBLK: rb = blk>>2 (6 rows), kq = blk&3 (96-wide k-segment).
//   role 0 (tid<128): PiP[kq][row][h]     role 1: PjTP[kq][b][h][a]
// tail blocks: Gc[b][h] = gctx[b] @ W1[773:901] + b1
__global__ __launch_bounds__(256, 4) void precompute_P(
    const float* __restrict__ coord, const float* __restrict__ goal,
    const float* __restrict__ frontier, const float* __restrict__ gctx,
    const float* __restrict__ W1, const float* __restrict__ b1,
    float* __restrict__ PiP, float* __restrict__ PjTP, float* __restrict__ Gc)
{
    const int blk = blockIdx.x;
    const int tid = threadIdx.x;

    if (blk >= KS * NROWBLK) {
        // ---- Gc block: one per b ----
        __shared__ float red[256];
        const int b = blk - KS * NROWBLK;
        const int h = tid & 127, part = tid >> 7;
        const float* g = gctx + b * ND + part * 64;
        const float* w = W1 + (size_t)(6 * ND + NREL + part * 64) * NH + h;
        float acc = 0.f;
#pragma unroll 8
        for (int d = 0; d < 64; ++d) acc += g[d] * w[d * NH];
        red[tid] = acc;
        __syncthreads();
        if (part == 0) Gc[b * NH + h] = red[h] + red[h + 128] + b1[h];
        return;
    }

    const int rb = blk >> 2;
    const int kq = blk & 3;              // 96-wide k-segment
    const int r0 = rb * ROWS;

    __shared__ __align__(16) float X[ROWS][96];

    // stage 6 rows x 96 k's of [coord|goal|frontier]
    for (int idx = tid; idx < ROWS * 96; idx += 256) {
        int r = idx / 96;
        int kk = idx - r * 96;
        int k = kq * 96 + kk;
        int s = k >> 7, d = k & 127;
        const float* src = (s == 0) ? coord : (s == 1) ? goal : frontier;
        X[r][kk] = src[(r0 + r) * ND + d];
    }
    __syncthreads();

    const int colLocal = tid & 127;
    const int role = tid >> 7;           // 0 = i-role, 1 = j-role
    const int roleOff = role * 128;

    float acc[ROWS];
#pragma unroll
    for (int r = 0; r < ROWS; r++) acc[r] = 0.f;

    auto seg = [&](int kkStart, int sChunk, int dStart, int len) {
        const float* wb = W1 + (size_t)(sChunk * 256 + roleOff + dStart) * NH + colLocal;
#pragma unroll 4
        for (int t = 0; t < len; t += 4) {
            float w0 = wb[0 * NH];
            float w1 = wb[1 * NH];
            float w2 = wb[2 * NH];
            float w3 = wb[3 * NH];
            wb += 4 * NH;
#pragma unroll
            for (int r = 0; r < ROWS; r++) {
                float4 x = *(const float4*)&X[r][kkStart + t];
                acc[r] += x.x * w0 + x.y * w1 + x.z * w2 + x.w * w3;
            }
        }
    };
    if (kq == 0)      { seg(0, 0, 0, 96); }
    else if (kq == 1) { seg(0, 0, 96, 32); seg(32, 1, 0, 64); }
    else if (kq == 2) { seg(0, 1, 64, 64); seg(64, 2, 0, 32); }
    else              { seg(0, 2, 32, 96); }

#pragma unroll
    for (int r = 0; r < ROWS; r++) {
        int row = r0 + r;
        if (role == 0) {
            PiP[((size_t)kq * NB * NA + row) * NH + colLocal] = acc[r];
        } else {
            int b = row / NA, a = row - b * NA;
            PjTP[(((size_t)kq * NB + b) * NH + colLocal) * NA + a] = acc[r];
        }
    }
}

// ---------------- Kernel 1b: combine the KS PjT partials ----------------
__global__ __launch_bounds__(256) void combine_PjT(
    const float* __restrict__ PjTP, float* __restrict__ PjT)
{
    const size_t e = (size_t)blockIdx.x * 256 + threadIdx.x;  // (b,h,a) flat
    const size_t n = (size_t)NB * NH * NA;
    float v = PjTP[e] + PjTP[n + e] + PjTP[2 * n + e] + PjTP[3 * n + e];
    PjT[e] = v;
}

// ---------------- Kernel 2: edge MLP + masked softmax, TI=2 i's/block ----------------
// 384 threads = (j = tid%192) x (h-half = tid/192).
__global__ __launch_bounds__(384, 4) void edge_kernel(
    const float* __restrict__ PiP, const float* __restrict__ PjT,
    const float* __restrict__ Gc, const float* __restrict__ W1,
    const float* __restrict__ W2, const float* __restrict__ b2v,
    const float* __restrict__ rel_feat, const int* __restrict__ rule_adj,
    const float* __restrict__ base_score,
    float* __restrict__ out_w, float* __restrict__ out_s, float* __restrict__ out_l)
{
    const int b  = blockIdx.x / (NA / TI);
    const int i0 = (blockIdx.x % (NA / TI)) * TI;
    const int tid = threadIdx.x;
    const int j = tid % NA;
    const int half = tid / NA;           // 0: h in [0,64), 1: h in [64,128)

    __shared__ __align__(16) float4 su1[NH];   // {wr0, wr1, wr2, wr3}
    __shared__ __align__(16) float4 su2[NH];   // {wr4, w2, pig0, pig1}
    __shared__ float s_part[2][TI][NA];
    __shared__ float redA[3], redB[3], redC[3];

    if (tid < NH) {
        const int h = tid;
        const int row0 = b * NA + i0;
        float pig0 = Gc[b * NH + h], pig1 = pig0;
#pragma unroll
        for (int kq = 0; kq < KS; ++kq) {
            pig0 += PiP[((size_t)kq * NB * NA + row0) * NH + h];
            pig1 += PiP[((size_t)kq * NB * NA + row0 + 1) * NH + h];
        }
        const float* wr = W1 + (size_t)(6 * ND) * NH + h;
        su1[h] = make_float4(wr[0 * NH], wr[1 * NH], wr[2 * NH], wr[3 * NH]);
        su2[h] = make_float4(wr[4 * NH], W2[h], pig0, pig1);
    }

    float r0v[NREL], r1v[NREL];
    {
        const float* rf0 = rel_feat + (((size_t)(b * NA + i0) * NA) + j) * NREL;
        const float* rf1 = rf0 + (size_t)NA * NREL;
#pragma unroll
        for (int r = 0; r < NREL; r++) { r0v[r] = rf0[r]; r1v[r] = rf1[r]; }
    }
    __syncthreads();

    const float* pjb = PjT + ((size_t)b * NH + half * 64) * NA + j;
    float acc0 = 0.f, acc1 = 0.f;
#pragma unroll 4
    for (int hh = 0; hh < 64; ++hh) {
        float p = pjb[hh * NA];
        float4 a = su1[half * 64 + hh];
        float4 c = su2[half * 64 + hh];
        float pre0 = c.z + p;
        pre0 += r0v[0] * a.x; pre0 += r0v[1] * a.y; pre0 += r0v[2] * a.z;
        pre0 += r0v[3] * a.w; pre0 += r0v[4] * c.x;
        float pre1 = c.w + p;
        pre1 += r1v[0] * a.x; pre1 += r1v[1] * a.y; pre1 += r1v[2] * a.z;
        pre1 += r1v[3] * a.w; pre1 += r1v[4] * c.x;
        acc0 += fmaxf(pre0, 0.f) * c.y;
        acc1 += fmaxf(pre1, 0.f) * c.y;
    }
    s_part[half][0][j] = acc0;
    s_part[half][1][j] = acc1;
    __syncthreads();

    const int wave = tid >> 6, lane = tid & 63;
    const float b2c = b2v[0];
    float scv[TI];
    int adjv[TI];
    if (tid < NA) {
#pragma unroll
        for (int ti = 0; ti < TI; ++ti) {
            const size_t row = (size_t)(b * NA + i0 + ti) * NA + tid;
            float lrn = s_part[0][ti][tid] + s_part[1][ti][tid] + b2c;
            out_l[row] = lrn;
            adjv[ti] = rule_adj[row];
            scv[ti] = adjv[ti] ? (base_score[row] + lrn) : -1e9f;
            out_s[row] = scv[ti];
        }
    }

#pragma unroll
    for (int ti = 0; ti < TI; ++ti) {
        float m = (tid < NA) ? scv[ti] : -3.4e38f;
#pragma unroll
        for (int off = 32; off > 0; off >>= 1) m = fmaxf(m, __shfl_xor(m, off, 64));
        if (lane == 0 && wave < 3) redA[wave] = m;
        __syncthreads();
        m = fmaxf(fmaxf(redA[0], redA[1]), redA[2]);

        float e = (tid < NA) ? __expf(scv[ti] - m) : 0.f;
        float S = e;
#pragma unroll
        for (int off = 32; off > 0; off >>= 1) S += __shfl_xor(S, off, 64);
        if (lane == 0 && wave < 3) redB[wave] = S;
        __syncthreads();
        S = redB[0] + redB[1] + redB[2];

        float wj = (tid < NA && adjv[ti]) ? e * (1.f / S) : 0.f;
        float sw = wj;
#pragma unroll
        for (int off = 32; off > 0; off >>= 1) sw += __shfl_xor(sw, off, 64);
        if (lane == 0 && wave < 3) redC[wave] = sw;
        __syncthreads();
        sw = redC[0] + redC[1] + redC[2];

        if (tid < NA)
            out_w[(size_t)(b * NA + i0 + ti) * NA + tid] = wj * (1.f / (sw + 1e-8f));
        __syncthreads();
    }
}

extern "C" void kernel_launch(void* const* d_in, const int* in_sizes, int n_in,
                              void* d_out, int out_size, void* d_ws, size_t ws_size,
                              hipStream_t stream) {
    const float* coord    = (const float*)d_in[0];
    const float* goal     = (const float*)d_in[1];
    const float* frontier = (const float*)d_in[2];
    const float* rel_feat = (const float*)d_in[3];
    const int*   rule_adj = (const int*)d_in[4];
    const float* base_sc  = (const float*)d_in[5];
    const float* gctx     = (const float*)d_in[6];
    const float* W1       = (const float*)d_in[7];
    const float* b1       = (const float*)d_in[8];
    const float* W2       = (const float*)d_in[9];
    const float* b2       = (const float*)d_in[10];

    float* PiP  = (float*)d_ws;                     // KS * 1536 * 128
    float* PjTP = PiP + KS * NB * NA * NH;          // KS * 8 * 128 * 192
    float* PjT  = PjTP + KS * NB * NH * NA;         // 8 * 128 * 192
    float* Gc   = PjT + NB * NH * NA;               // 8 * 128

    float* out_w = (float*)d_out;
    float* out_s = out_w + NB * NA * NA;
    float* out_l = out_s + NB * NA * NA;

    precompute_P<<<KS * NROWBLK + NB, 256, 0, stream>>>(coord, goal, frontier, gctx,
                                                        W1, b1, PiP, PjTP, Gc);
    combine_PjT<<<(NB * NH * NA) / 256, 256, 0, stream>>>(PjTP, PjT);
    edge_kernel<<<NB * (NA / TI), 384, 0, stream>>>(PiP, PjT, Gc, W1, W2, b2, rel_feat,
                                                    rule_adj, base_sc, out_w, out_s, out_l);
}

// Round 5
// 115.522 us; speedup vs baseline: 1.0285x; 1.0285x over previous
//
#include <hip/hip_runtime.h>
#include <math.h>

#define NB 8
#define NA 192
#define ND 128
#define NREL 5
#define NH 128
#define ROWS 6
#define NROWBLK ((NB * NA) / ROWS)      // 256 row-blocks, x2 k-halves = 512 blocks
// fan_in = 6*ND + NREL + ND = 901
// W1 rows: [0:128) ci, [128:256) cj, [256:384) gi, [384:512) gj,
//          [512:640) fi, [640:768) fj, [768:773) rel, [773:901) gc

// ---------------- Kernel 1: k-split partial projections + Gc ----------------
// blk < 2*NROWBLK: rb = blk>>1 (6 rows), kh = blk&1 (k-half of 384).
//   role 0 (tid<128): PiP[kh][row][h]     role 1: PjTP[kh][b][h][a]
// tail blocks: Gc[b][h] = gctx[b] @ W1[773:901] + b1
__global__ __launch_bounds__(256, 4) void precompute_P(
    const float* __restrict__ coord, const float* __restrict__ goal,
    const float* __restrict__ frontier, const float* __restrict__ gctx,
    const float* __restrict__ W1, const float* __restrict__ b1,
    float* __restrict__ PiP, float* __restrict__ PjTP, float* __restrict__ Gc)
{
    const int blk = blockIdx.x;
    const int tid = threadIdx.x;

    if (blk >= 2 * NROWBLK) {
        // ---- Gc block: one per b ----
        __shared__ float red[256];
        const int b = blk - 2 * NROWBLK;
        const int h = tid & 127, part = tid >> 7;
        const float* g = gctx + b * ND + part * 64;
        const float* w = W1 + (size_t)(6 * ND + NREL + part * 64) * NH + h;
        float acc = 0.f;
#pragma unroll 8
        for (int d = 0; d < 64; ++d) acc += g[d] * w[d * NH];
        red[tid] = acc;
        __syncthreads();
        if (part == 0) Gc[b * NH + h] = red[h] + red[h + 128] + b1[h];
        return;
    }

    const int rb = blk >> 1;
    const int kh = blk & 1;              // which half of k = 0..383
    const int r0 = rb * ROWS;

    __shared__ __align__(16) float X[ROWS][192];

    // stage 6 rows x 192 k's of [coord|goal|frontier]
    for (int idx = tid; idx < ROWS * 192; idx += 256) {
        int r = idx / 192;
        int kk = idx - r * 192;
        int k = kh * 192 + kk;
        int s = k >> 7, d = k & 127;
        const float* src = (s == 0) ? coord : (s == 1) ? goal : frontier;
        X[r][kk] = src[(r0 + r) * ND + d];
    }
    __syncthreads();

    const int colLocal = tid & 127;
    const int role = tid >> 7;           // 0 = i-role, 1 = j-role
    const int roleOff = role * 128;

    float acc[ROWS];
#pragma unroll
    for (int r = 0; r < ROWS; r++) acc[r] = 0.f;

    auto seg = [&](int kkStart, int sChunk, int dStart, int len) {
        const float* wb = W1 + (size_t)(sChunk * 256 + roleOff + dStart) * NH + colLocal;
#pragma unroll 4
        for (int t = 0; t < len; t += 4) {
            float w0 = wb[0 * NH];
            float w1 = wb[1 * NH];
            float w2 = wb[2 * NH];
            float w3 = wb[3 * NH];
            wb += 4 * NH;
#pragma unroll
            for (int r = 0; r < ROWS; r++) {
                float4 x = *(const float4*)&X[r][kkStart + t];
                acc[r] += x.x * w0 + x.y * w1 + x.z * w2 + x.w * w3;
            }
        }
    };
    if (kh == 0) { seg(0, 0, 0, 128); seg(128, 1, 0, 64); }
    else         { seg(0, 1, 64, 64); seg(64, 2, 0, 128); }

#pragma unroll
    for (int r = 0; r < ROWS; r++) {
        int row = r0 + r;
        if (role == 0) {
            PiP[((size_t)kh * NB * NA + row) * NH + colLocal] = acc[r];
        } else {
            int b = row / NA, a = row - b * NA;
            PjTP[(((size_t)kh * NB + b) * NH + colLocal) * NA + a] = acc[r];
        }
    }
}

// ---------------- Kernel 2: per-(b,i) edge MLP + masked softmax ----------------
// 192 threads, lane = j. Combines the two k-half partials on the fly.
__global__ __launch_bounds__(192) void edge_kernel(
    const float* __restrict__ PiP, const float* __restrict__ PjTP,
    const float* __restrict__ Gc, const float* __restrict__ W1,
    const float* __restrict__ W2, const float* __restrict__ b2v,
    const float* __restrict__ rel_feat, const int* __restrict__ rule_adj,
    const float* __restrict__ base_score,
    float* __restrict__ out_w, float* __restrict__ out_s, float* __restrict__ out_l)
{
    const int bi = blockIdx.x;           // b*NA + i
    const int b = bi / NA;
    const int tid = threadIdx.x;         // = j, 0..191

    __shared__ float4 su1[NH];           // {pig, wrel0, wrel1, wrel2}
    __shared__ float4 su2[NH];           // {wrel3, wrel4, w2, 0}
    __shared__ float redA[3], redB[3], redC[3];

    if (tid < NH) {
        float pig = PiP[(size_t)bi * NH + tid]
                  + PiP[(size_t)(NB * NA + bi) * NH + tid]
                  + Gc[b * NH + tid];
        const float* wr = W1 + (size_t)(6 * ND) * NH + tid;
        su1[tid] = make_float4(pig, wr[0 * NH], wr[1 * NH], wr[2 * NH]);
        su2[tid] = make_float4(wr[3 * NH], wr[4 * NH], W2[tid], 0.f);
    }

    float rel[NREL];
    const float* rf = rel_feat + ((size_t)bi * NA + tid) * NREL;
#pragma unroll
    for (int r = 0; r < NREL; r++) rel[r] = rf[r];

    __syncthreads();

    const float* pj0 = PjTP + (size_t)b * NH * NA + tid;
    const float* pj1 = pj0 + (size_t)NB * NH * NA;
    float acc = 0.f;
#pragma unroll 8
    for (int h = 0; h < NH; ++h) {
        float p = pj0[h * NA] + pj1[h * NA];
        float4 a = su1[h];
        float4 c = su2[h];
        float pre = a.x + p;
        pre += rel[0] * a.y;
        pre += rel[1] * a.z;
        pre += rel[2] * a.w;
        pre += rel[3] * c.x;
        pre += rel[4] * c.y;
        acc += fmaxf(pre, 0.f) * c.z;
    }
    float learned = acc + b2v[0];
    out_l[(size_t)bi * NA + tid] = learned;

    const int adj = rule_adj[(size_t)bi * NA + tid];
    const float sc = adj ? (base_score[(size_t)bi * NA + tid] + learned) : -1e9f;
    out_s[(size_t)bi * NA + tid] = sc;

    const int wave = tid >> 6, lane = tid & 63;

    // max over 192 lanes
    float m = sc;
#pragma unroll
    for (int off = 32; off > 0; off >>= 1) m = fmaxf(m, __shfl_xor(m, off, 64));
    if (lane == 0) redA[wave] = m;
    __syncthreads();
    m = fmaxf(fmaxf(redA[0], redA[1]), redA[2]);

    // sum of exp
    float e = __expf(sc - m);
    float S = e;
#pragma unroll
    for (int off = 32; off > 0; off >>= 1) S += __shfl_xor(S, off, 64);
    if (lane == 0) redB[wave] = S;
    __syncthreads();
    S = redB[0] + redB[1] + redB[2];

    // masked renorm
    float wj = adj ? e * (1.f / S) : 0.f;
    float sw = wj;
#pragma unroll
    for (int off = 32; off > 0; off >>= 1) sw += __shfl_xor(sw, off, 64);
    if (lane == 0) redC[wave] = sw;
    __syncthreads();
    sw = redC[0] + redC[1] + redC[2];

    out_w[(size_t)bi * NA + tid] = wj * (1.f / (sw + 1e-8f));
}

extern "C" void kernel_launch(void* const* d_in, const int* in_sizes, int n_in,
                              void* d_out, int out_size, void* d_ws, size_t ws_size,
                              hipStream_t stream) {
    const float* coord    = (const float*)d_in[0];
    const float* goal     = (const float*)d_in[1];
    const float* frontier = (const float*)d_in[2];
    const float* rel_feat = (const float*)d_in[3];
    const int*   rule_adj = (const int*)d_in[4];
    const float* base_sc  = (const float*)d_in[5];
    const float* gctx     = (const float*)d_in[6];
    const float* W1       = (const float*)d_in[7];
    const float* b1       = (const float*)d_in[8];
    const float* W2       = (const float*)d_in[9];
    const float* b2       = (const float*)d_in[10];

    float* PiP  = (float*)d_ws;                   // 2 * 1536 * 128 floats
    float* PjTP = PiP + 2 * NB * NA * NH;         // 2 * 8 * 128 * 192 floats
    float* Gc   = PjTP + 2 * NB * NH * NA;        // 8 * 128

    float* out_w = (float*)d_out;
    float* out_s = out_w + NB * NA * NA;
    float* out_l = out_s + NB * NA * NA;

    precompute_P<<<2 * NROWBLK + NB, 256, 0, stream>>>(coord, goal, frontier, gctx,
                                                       W1, b1, PiP, PjTP, Gc);
    edge_kernel<<<NB * NA, 192, 0, stream>>>(PiP, PjTP, Gc, W1, W2, b2, rel_feat,
                                             rule_adj, base_sc, out_w, out_s, out_l);
}

// Round 6
// 112.414 us; speedup vs baseline: 1.0569x; 1.0277x over previous
//
#include <hip/hip_runtime.h>
#include <math.h>

#define NB 8
#define NA 192
#define ND 128
#define NREL 5
#define NH 128
#define ROWS 3
#define NROWBLK ((NB * NA) / ROWS)      // 512 row-blocks, x2 k-halves = 1024 blocks
#define TI 2                            // i-tile in edge kernel
// fan_in = 6*ND + NREL + ND = 901
// W1 rows: [0:128) ci, [128:256) cj, [256:384) gi, [384:512) gj,
//          [512:640) fi, [640:768) fj, [768:773) rel, [773:901) gc

// ---------------- Kernel 1: k-split partial projections + Gc ----------------
// blk < 2*NROWBLK: rb = blk>>1 (3 rows), kh = blk&1 (k-half of 384).
//   role 0 (tid<128): PiP[kh][row][h]     role 1: PjTP[kh][b][h][a]
// tail blocks: Gc[b][h] = gctx[b] @ W1[773:901] + b1
__global__ __launch_bounds__(256, 4) void precompute_P(
    const float* __restrict__ coord, const float* __restrict__ goal,
    const float* __restrict__ frontier, const float* __restrict__ gctx,
    const float* __restrict__ W1, const float* __restrict__ b1,
    float* __restrict__ PiP, float* __restrict__ PjTP, float* __restrict__ Gc)
{
    const int blk = blockIdx.x;
    const int tid = threadIdx.x;

    if (blk >= 2 * NROWBLK) {
        // ---- Gc block: one per b ----
        __shared__ float red[256];
        const int b = blk - 2 * NROWBLK;
        const int h = tid & 127, part = tid >> 7;
        const float* g = gctx + b * ND + part * 64;
        const float* w = W1 + (size_t)(6 * ND + NREL + part * 64) * NH + h;
        float acc = 0.f;
#pragma unroll 8
        for (int d = 0; d < 64; ++d) acc += g[d] * w[d * NH];
        red[tid] = acc;
        __syncthreads();
        if (part == 0) Gc[b * NH + h] = red[h] + red[h + 128] + b1[h];
        return;
    }

    const int rb = blk >> 1;
    const int kh = blk & 1;              // which half of k = 0..383
    const int r0 = rb * ROWS;

    __shared__ __align__(16) float X[ROWS][192];

    // stage 3 rows x 192 k's of [coord|goal|frontier]
    for (int idx = tid; idx < ROWS * 192; idx += 256) {
        int r = idx / 192;
        int kk = idx - r * 192;
        int k = kh * 192 + kk;
        int s = k >> 7, d = k & 127;
        const float* src = (s == 0) ? coord : (s == 1) ? goal : frontier;
        X[r][kk] = src[(r0 + r) * ND + d];
    }
    __syncthreads();

    const int colLocal = tid & 127;
    const int role = tid >> 7;           // 0 = i-role, 1 = j-role
    const int roleOff = role * 128;

    float acc[ROWS];
#pragma unroll
    for (int r = 0; r < ROWS; r++) acc[r] = 0.f;

    auto seg = [&](int kkStart, int sChunk, int dStart, int len) {
        const float* wb = W1 + (size_t)(sChunk * 256 + roleOff + dStart) * NH + colLocal;
#pragma unroll 4
        for (int t = 0; t < len; t += 4) {
            float w0 = wb[0 * NH];
            float w1 = wb[1 * NH];
            float w2 = wb[2 * NH];
            float w3 = wb[3 * NH];
            wb += 4 * NH;
#pragma unroll
            for (int r = 0; r < ROWS; r++) {
                float4 x = *(const float4*)&X[r][kkStart + t];
                acc[r] += x.x * w0 + x.y * w1 + x.z * w2 + x.w * w3;
            }
        }
    };
    if (kh == 0) { seg(0, 0, 0, 128); seg(128, 1, 0, 64); }
    else         { seg(0, 1, 64, 64); seg(64, 2, 0, 128); }

#pragma unroll
    for (int r = 0; r < ROWS; r++) {
        int row = r0 + r;
        if (role == 0) {
            PiP[((size_t)kh * NB * NA + row) * NH + colLocal] = acc[r];
        } else {
            int b = row / NA, a = row - b * NA;
            PjTP[(((size_t)kh * NB + b) * NH + colLocal) * NA + a] = acc[r];
        }
    }
}

// ---------------- Kernel 2: edge MLP + masked softmax, TI=2 i's/block ----------------
// 384 threads = (j = tid%192) x (h-half = tid/192). Combines the 2 k-half
// partials of PjT on the fly (no separate combine kernel).
__global__ __launch_bounds__(384, 4) void edge_kernel(
    const float* __restrict__ PiP, const float* __restrict__ PjTP,
    const float* __restrict__ Gc, const float* __restrict__ W1,
    const float* __restrict__ W2, const float* __restrict__ b2v,
    const float* __restrict__ rel_feat, const int* __restrict__ rule_adj,
    const float* __restrict__ base_score,
    float* __restrict__ out_w, float* __restrict__ out_s, float* __restrict__ out_l)
{
    const int b  = blockIdx.x / (NA / TI);
    const int i0 = (blockIdx.x % (NA / TI)) * TI;
    const int tid = threadIdx.x;
    const int j = tid % NA;
    const int half = tid / NA;           // 0: h in [0,64), 1: h in [64,128)

    __shared__ __align__(16) float4 su1[NH];   // {wr0, wr1, wr2, wr3}
    __shared__ __align__(16) float4 su2[NH];   // {wr4, w2, pig0, pig1}
    __shared__ float s_part[2][TI][NA];
    __shared__ float redA[3], redB[3], redC[3];

    if (tid < NH) {
        const int h = tid;
        const int row0 = b * NA + i0;
        float pig0 = Gc[b * NH + h]
                   + PiP[(size_t)row0 * NH + h]
                   + PiP[(size_t)(NB * NA + row0) * NH + h];
        float pig1 = Gc[b * NH + h]
                   + PiP[(size_t)(row0 + 1) * NH + h]
                   + PiP[(size_t)(NB * NA + row0 + 1) * NH + h];
        const float* wr = W1 + (size_t)(6 * ND) * NH + h;
        su1[h] = make_float4(wr[0 * NH], wr[1 * NH], wr[2 * NH], wr[3 * NH]);
        su2[h] = make_float4(wr[4 * NH], W2[h], pig0, pig1);
    }

    float r0v[NREL], r1v[NREL];
    {
        const float* rf0 = rel_feat + (((size_t)(b * NA + i0) * NA) + j) * NREL;
        const float* rf1 = rf0 + (size_t)NA * NREL;
#pragma unroll
        for (int r = 0; r < NREL; r++) { r0v[r] = rf0[r]; r1v[r] = rf1[r]; }
    }
    __syncthreads();

    const float* pjb0 = PjTP + ((size_t)b * NH + half * 64) * NA + j;
    const float* pjb1 = pjb0 + (size_t)NB * NH * NA;
    float acc0 = 0.f, acc1 = 0.f;
#pragma unroll 4
    for (int hh = 0; hh < 64; ++hh) {
        float p = pjb0[hh * NA] + pjb1[hh * NA];
        float4 a = su1[half * 64 + hh];
        float4 c = su2[half * 64 + hh];
        float pre0 = c.z + p;
        pre0 += r0v[0] * a.x; pre0 += r0v[1] * a.y; pre0 += r0v[2] * a.z;
        pre0 += r0v[3] * a.w; pre0 += r0v[4] * c.x;
        float pre1 = c.w + p;
        pre1 += r1v[0] * a.x; pre1 += r1v[1] * a.y; pre1 += r1v[2] * a.z;
        pre1 += r1v[3] * a.w; pre1 += r1v[4] * c.x;
        acc0 += fmaxf(pre0, 0.f) * c.y;
        acc1 += fmaxf(pre1, 0.f) * c.y;
    }
    s_part[half][0][j] = acc0;
    s_part[half][1][j] = acc1;
    __syncthreads();

    const int wave = tid >> 6, lane = tid & 63;
    const float b2c = b2v[0];
    float scv[TI];
    int adjv[TI];
    if (tid < NA) {
#pragma unroll
        for (int ti = 0; ti < TI; ++ti) {
            const size_t row = (size_t)(b * NA + i0 + ti) * NA + tid;
            float lrn = s_part[0][ti][tid] + s_part[1][ti][tid] + b2c;
            out_l[row] = lrn;
            adjv[ti] = rule_adj[row];
            scv[ti] = adjv[ti] ? (base_score[row] + lrn) : -1e9f;
            out_s[row] = scv[ti];
        }
    }

#pragma unroll
    for (int ti = 0; ti < TI; ++ti) {
        float m = (tid < NA) ? scv[ti] : -3.4e38f;
#pragma unroll
        for (int off = 32; off > 0; off >>= 1) m = fmaxf(m, __shfl_xor(m, off, 64));
        if (lane == 0 && wave < 3) redA[wave] = m;
        __syncthreads();
        m = fmaxf(fmaxf(redA[0], redA[1]), redA[2]);

        float e = (tid < NA) ? __expf(scv[ti] - m) : 0.f;
        float S = e;
#pragma unroll
        for (int off = 32; off > 0; off >>= 1) S += __shfl_xor(S, off, 64);
        if (lane == 0 && wave < 3) redB[wave] = S;
        __syncthreads();
        S = redB[0] + redB[1] + redB[2];

        float wj = (tid < NA && adjv[ti]) ? e * (1.f / S) : 0.f;
        float sw = wj;
#pragma unroll
        for (int off = 32; off > 0; off >>= 1) sw += __shfl_xor(sw, off, 64);
        if (lane == 0 && wave < 3) redC[wave] = sw;
        __syncthreads();
        sw = redC[0] + redC[1] + redC[2];

        if (tid < NA)
            out_w[(size_t)(b * NA + i0 + ti) * NA + tid] = wj * (1.f / (sw + 1e-8f));
        __syncthreads();
    }
}

extern "C" void kernel_launch(void* const* d_in, const int* in_sizes, int n_in,
                              void* d_out, int out_size, void* d_ws, size_t ws_size,
                              hipStream_t stream) {
    const float* coord    = (const float*)d_in[0];
    const float* goal     = (const float*)d_in[1];
    const float* frontier = (const float*)d_in[2];
    const float* rel_feat = (const float*)d_in[3];
    const int*   rule_adj = (const int*)d_in[4];
    const float* base_sc  = (const float*)d_in[5];
    const float* gctx     = (const float*)d_in[6];
    const float* W1       = (const float*)d_in[7];
    const float* b1       = (const float*)d_in[8];
    const float* W2       = (const float*)d_in[9];
    const float* b2       = (const float*)d_in[10];

    float* PiP  = (float*)d_ws;                   // 2 * 1536 * 128 floats
    float* PjTP = PiP + 2 * NB * NA * NH;         // 2 * 8 * 128 * 192 floats
    float* Gc   = PjTP + 2 * NB * NH * NA;        // 8 * 128

    float* out_w = (float*)d_out;
    float* out_s = out_w + NB * NA * NA;
    float* out_l = out_s + NB * NA * NA;

    precompute_P<<<2 * NROWBLK + NB, 256, 0, stream>>>(coord, goal, frontier, gctx,
                                                       W1, b1, PiP, PjTP, Gc);
    edge_kernel<<<NB * (NA / TI), 384, 0, stream>>>(PiP, PjTP, Gc, W1, W2, b2, rel_feat,
                                                    rule_adj, base_sc, out_w, out_s, out_l);
}